// Round 5
// baseline (700.479 us; speedup 1.0000x reference)
//
#include <hip/hip_runtime.h>

#define S_TOK 8192
#define BATCH 8
#define LSEQ 1024
#define HID 2048
#define NH 16
#define NKV 4
#define DHEAD 128
#define QKV_W 3072
#define SCALE_F 0.08838834764831845f

typedef __attribute__((ext_vector_type(8))) unsigned short u16x8;
typedef __attribute__((ext_vector_type(8))) __bf16 bf16x8;
typedef __attribute__((ext_vector_type(4))) float f32x4;

__device__ __forceinline__ unsigned short f2bf(float f) {
  unsigned u = __builtin_bit_cast(unsigned, f);
  unsigned r = u + 0x7fffu + ((u >> 16) & 1u);
  return (unsigned short)(r >> 16);
}
__device__ __forceinline__ float bf2f(unsigned short h) {
  return __builtin_bit_cast(float, (unsigned)h << 16);
}

__device__ __forceinline__ void async16(const void* g, void* l) {
  __builtin_amdgcn_global_load_lds(
      (const __attribute__((address_space(1))) void*)g,
      (__attribute__((address_space(3))) void*)l, 16, 0, 0);
}

// ---------------- fp32 -> bf16 converters ----------------
__global__ __launch_bounds__(256) void conv_f2b(const float* __restrict__ src,
                                                unsigned short* __restrict__ dst,
                                                int n8) {
  int t = blockIdx.x * 256 + threadIdx.x;
  if (t >= n8) return;
  const f32x4* s4 = (const f32x4*)(src + (size_t)t * 8);
  f32x4 v0 = s4[0], v1 = s4[1];
  u16x8 o;
#pragma unroll
  for (int j = 0; j < 4; ++j) { o[j] = f2bf(v0[j]); o[4 + j] = f2bf(v1[j]); }
  *(u16x8*)(dst + (size_t)t * 8) = o;
}

// concat wq(2048,2048) wk(512,2048) wv(512,2048) -> bf16 (3072,2048)
__global__ __launch_bounds__(256) void conv_w3(const float* __restrict__ wq,
                                               const float* __restrict__ wk,
                                               const float* __restrict__ wv,
                                               unsigned short* __restrict__ dst,
                                               int n8) {
  int t = blockIdx.x * 256 + threadIdx.x;
  if (t >= n8) return;
  size_t idx = (size_t)t * 8;
  int row = (int)(idx >> 11);
  int col = (int)(idx & 2047);
  const float* src;
  if (row < 2048)      src = wq + ((size_t)row << 11) + col;
  else if (row < 2560) src = wk + ((size_t)(row - 2048) << 11) + col;
  else                 src = wv + ((size_t)(row - 2560) << 11) + col;
  const f32x4* s4 = (const f32x4*)src;
  f32x4 v0 = s4[0], v1 = s4[1];
  u16x8 o;
#pragma unroll
  for (int j = 0; j < 4; ++j) { o[j] = f2bf(v0[j]); o[4 + j] = f2bf(v1[j]); }
  *(u16x8*)(dst + idx) = o;
}

// ---------------- GEMM: C[M,N] = A[M,K] * B[N,K]^T (+bias) ----------------
// 128x128 tile, BK=32, 256 threads (4 waves, 2x2 of 64x64)
template <bool ADD_BIAS, bool OUT_BF16>
__global__ __launch_bounds__(256) void gemm_bt(const unsigned short* __restrict__ A,
                                               const unsigned short* __restrict__ Bw,
                                               const float* __restrict__ bias,
                                               void* __restrict__ Cout,
                                               int M, int N, int K) {
  __shared__ unsigned short A_lds[128 * 32];
  __shared__ unsigned short B_lds[128 * 32];
  const int tid = threadIdx.x;
  const int w = tid >> 6, lane = tid & 63;
  const int lr = lane & 15, lg = lane >> 4;
  const int wr = w >> 1, wc = w & 1;
  const int m0 = blockIdx.y * 128, n0 = blockIdx.x * 128;

  f32x4 acc[4][4];
#pragma unroll
  for (int mi = 0; mi < 4; ++mi)
#pragma unroll
    for (int nj = 0; nj < 4; ++nj) acc[mi][nj] = (f32x4){0.f, 0.f, 0.f, 0.f};

  const int nk = K >> 5;
  const int srow = (lane >> 2);       // 0..15 within chunk
  const int scol = (lane & 3) * 8;    // element col
  for (int kt = 0; kt < nk; ++kt) {
#pragma unroll
    for (int q = 0; q < 2; ++q) {
      int chunk = w * 2 + q;              // 0..7, 16 rows each
      int row = chunk * 16 + srow;
      async16(A + (size_t)(m0 + row) * K + kt * 32 + scol, &A_lds[chunk * 512]);
      async16(Bw + (size_t)(n0 + row) * K + kt * 32 + scol, &B_lds[chunk * 512]);
    }
    __syncthreads();
    bf16x8 a[4], bb[4];
#pragma unroll
    for (int mi = 0; mi < 4; ++mi)
      a[mi] = *(const bf16x8*)&A_lds[(wr * 64 + mi * 16 + lr) * 32 + lg * 8];
#pragma unroll
    for (int nj = 0; nj < 4; ++nj)
      bb[nj] = *(const bf16x8*)&B_lds[(wc * 64 + nj * 16 + lr) * 32 + lg * 8];
#pragma unroll
    for (int mi = 0; mi < 4; ++mi)
#pragma unroll
      for (int nj = 0; nj < 4; ++nj)
        acc[mi][nj] = __builtin_amdgcn_mfma_f32_16x16x32_bf16(a[mi], bb[nj], acc[mi][nj], 0, 0, 0);
    __syncthreads();
  }

#pragma unroll
  for (int mi = 0; mi < 4; ++mi)
#pragma unroll
    for (int nj = 0; nj < 4; ++nj)
#pragma unroll
      for (int j = 0; j < 4; ++j) {
        int row = m0 + wr * 64 + mi * 16 + lg * 4 + j;
        int col = n0 + wc * 64 + nj * 16 + lr;
        float v = acc[mi][nj][j];
        if (ADD_BIAS) v += bias[col];
        if (OUT_BF16)
          ((unsigned short*)Cout)[(size_t)row * N + col] = f2bf(v);
        else
          ((float*)Cout)[(size_t)row * N + col] = v;
      }
}

// ---------------- RoPE in-place on bf16 qkv (first 20 head-cols) ----------------
__global__ __launch_bounds__(256) void rope_k(unsigned short* __restrict__ qkv,
                                              const float* __restrict__ fc,
                                              const int* __restrict__ pid) {
  int t = blockIdx.x * 256 + threadIdx.x;  // 8192*20*8 threads
  int j0 = (t & 7) << 3;
  int hh = (t >> 3) % 20;
  int s = t / 160;
  if (s >= S_TOK) return;
  int sec = (j0 < 16) ? 0 : (j0 < 40 ? 1 : 2);
  int pos = pid[sec * S_TOK + s];
  const float* cs = fc + ((size_t)pos * 64 + j0) * 2;
  unsigned short* p = qkv + (size_t)s * QKV_W + hh * 128 + j0;
  u16x8 t1 = *(const u16x8*)p;
  u16x8 t2 = *(const u16x8*)(p + 64);
  u16x8 o1, o2;
#pragma unroll
  for (int j = 0; j < 8; ++j) {
    float c = cs[2 * j], sn = cs[2 * j + 1];
    float x1 = bf2f(t1[j]), x2 = bf2f(t2[j]);
    o1[j] = f2bf(x1 * c - x2 * sn);
    o2[j] = f2bf(x2 * c + x1 * sn);
  }
  *(u16x8*)p = o1;
  *(u16x8*)(p + 64) = o2;
}

// ---------------- causal GQA flash attention ----------------
// block: 256 thr (4 waves), QBLK=128 (32 rows/wave), KBLK=64
// Double-buffered K (global_load_lds, pre-swizzled source) and V (reg-staged
// transposed writes, round-2-proven involution). Prefetch tile t+1 at top of
// iteration t; V LDS-writes deferred until after PV (T14 split).
__global__ __launch_bounds__(256) void attn_fwd(const unsigned short* __restrict__ qkv,
                                                unsigned short* __restrict__ aout) {
  __shared__ unsigned short K_lds[2][8192];   // [kv][128] swizzled, 16KB each
  __shared__ unsigned short V_T[2][8192];     // [d][kv]   swizzled, 16KB each
  __shared__ unsigned short P_lds[4 * 2048];  // per-wave [32][64] swizzled
  char* Pb = (char*)P_lds;
  const int tid = threadIdx.x, w = tid >> 6, lane = tid & 63;
  const int lr = lane & 15, lg = lane >> 4;
  const int q0 = (7 - (int)blockIdx.x) * 128;   // longest-first
  const int h = blockIdx.y, b = blockIdx.z, kvh = h >> 2;
  const size_t kvbase = (size_t)(b * LSEQ) * QKV_W;

#define STAGE_K(bf, k0_)                                                                   \
  {                                                                                        \
    _Pragma("unroll") for (int c4 = 0; c4 < 4; ++c4) {                                     \
      int c = w * 4 + c4;                                                                  \
      int row = c * 4 + lg;                                                                \
      int colE = (lr * 8) ^ ((row & 7) * 8);                                               \
      async16(qkv + kvbase + (size_t)((k0_) + row) * QKV_W + HID + kvh * 128 + colE,       \
              &K_lds[bf][c * 512]);                                                        \
    }                                                                                      \
  }

#define LOAD_V(k0_)                                                                        \
  {                                                                                        \
    _Pragma("unroll") for (int r = 0; r < 4; ++r) {                                        \
      int d0 = (r * 4 + w) * 8;                                                            \
      vreg[r] = *(const u16x8*)(qkv + kvbase + (size_t)((k0_) + lane) * QKV_W + HID +      \
                                NKV * 128 + kvh * 128 + d0);                               \
    }                                                                                      \
  }

#define WRITE_V(bf)                                                                        \
  {                                                                                        \
    char* Vb_ = (char*)&V_T[bf][0];                                                        \
    _Pragma("unroll") for (int r = 0; r < 4; ++r) {                                        \
      int d0 = (r * 4 + w) * 8;                                                            \
      _Pragma("unroll") for (int j = 0; j < 8; ++j)                                        \
          *(unsigned short*)(Vb_ + (d0 + j) * 128 + ((lane * 2) ^ (j << 4))) = vreg[r][j]; \
    }                                                                                      \
  }

  // Q fragments in registers: rows w*32 + mi*16 + lr, d = kk*32 + lg*8
  bf16x8 qf[2][4];
#pragma unroll
  for (int mi = 0; mi < 2; ++mi)
#pragma unroll
    for (int kk = 0; kk < 4; ++kk)
      qf[mi][kk] = *(const bf16x8*)(qkv + (size_t)(b * LSEQ + q0 + w * 32 + mi * 16 + lr) * QKV_W +
                                    h * 128 + kk * 32 + lg * 8);

  f32x4 o[2][8];
#pragma unroll
  for (int mi = 0; mi < 2; ++mi)
#pragma unroll
    for (int nj = 0; nj < 8; ++nj) o[mi][nj] = (f32x4){0.f, 0.f, 0.f, 0.f};
  float m_run[2][4], l_run[2][4];
#pragma unroll
  for (int mi = 0; mi < 2; ++mi)
#pragma unroll
    for (int j = 0; j < 4; ++j) { m_run[mi][j] = -1e30f; l_run[mi][j] = 0.f; }

  u16x8 vreg[4];
  STAGE_K(0, 0);
  LOAD_V(0);
  WRITE_V(0);
  __syncthreads();

  const int ntiles = (q0 >> 6) + 2;
  for (int kt = 0; kt < ntiles; ++kt) {
    const int cb = kt & 1;
    const int k0 = kt * 64;
    const bool more = (kt + 1 < ntiles);
    if (more) {
      STAGE_K(cb ^ 1, k0 + 64);   // lands at end-of-iter barrier (vmcnt drain)
      LOAD_V(k0 + 64);            // regs; consumed by WRITE_V after PV
    }

    char* Kb = (char*)&K_lds[cb][0];
    // S = Q K^T  (per wave: 32 x 64)
    f32x4 s[2][4];
#pragma unroll
    for (int mi = 0; mi < 2; ++mi)
#pragma unroll
      for (int nj = 0; nj < 4; ++nj) s[mi][nj] = (f32x4){0.f, 0.f, 0.f, 0.f};
#pragma unroll
    for (int kk = 0; kk < 4; ++kk) {
#pragma unroll
      for (int nj = 0; nj < 4; ++nj) {
        bf16x8 kb = *(const bf16x8*)(Kb + (nj * 16 + lr) * 256 +
                                     ((kk * 64 + lg * 16) ^ ((lr & 7) << 4)));
        s[0][nj] = __builtin_amdgcn_mfma_f32_16x16x32_bf16(qf[0][kk], kb, s[0][nj], 0, 0, 0);
        s[1][nj] = __builtin_amdgcn_mfma_f32_16x16x32_bf16(qf[1][kk], kb, s[1][nj], 0, 0, 0);
      }
    }

    // online softmax (rows: mi*16 + lg*4 + j, cols: nj*16 + lr)
    float sf[2][4];
#pragma unroll
    for (int mi = 0; mi < 2; ++mi) {
#pragma unroll
      for (int j = 0; j < 4; ++j) {
        int qg = q0 + w * 32 + mi * 16 + lg * 4 + j;
        float rm = -1e30f;
#pragma unroll
        for (int nj = 0; nj < 4; ++nj) {
          int kg = k0 + nj * 16 + lr;
          float v = s[mi][nj][j] * SCALE_F;
          v = (kg > qg) ? -1e30f : v;
          s[mi][nj][j] = v;
          rm = fmaxf(rm, v);
        }
        rm = fmaxf(rm, __shfl_xor(rm, 1, 64));
        rm = fmaxf(rm, __shfl_xor(rm, 2, 64));
        rm = fmaxf(rm, __shfl_xor(rm, 4, 64));
        rm = fmaxf(rm, __shfl_xor(rm, 8, 64));
        float mn = fmaxf(m_run[mi][j], rm);
        float sc = __expf(m_run[mi][j] - mn);
        m_run[mi][j] = mn;
        float rs = 0.f;
#pragma unroll
        for (int nj = 0; nj < 4; ++nj) {
          float p = __expf(s[mi][nj][j] - mn);
          s[mi][nj][j] = p;
          rs += p;
        }
        rs += __shfl_xor(rs, 1, 64);
        rs += __shfl_xor(rs, 2, 64);
        rs += __shfl_xor(rs, 4, 64);
        rs += __shfl_xor(rs, 8, 64);
        l_run[mi][j] = l_run[mi][j] * sc + rs;
        sf[mi][j] = sc;
      }
    }
    // rescale O
#pragma unroll
    for (int mi = 0; mi < 2; ++mi)
#pragma unroll
      for (int nj = 0; nj < 8; ++nj)
#pragma unroll
        for (int j = 0; j < 4; ++j) o[mi][nj][j] *= sf[mi][j];
    // write P to per-wave LDS (bf16, swizzled)
#pragma unroll
    for (int mi = 0; mi < 2; ++mi)
#pragma unroll
      for (int nj = 0; nj < 4; ++nj)
#pragma unroll
        for (int j = 0; j < 4; ++j) {
          int prow = mi * 16 + lg * 4 + j;
          *(unsigned short*)(Pb + w * 4096 + prow * 128 +
                             (((nj * 16 + lr) * 2) ^ ((prow & 7) << 4))) = f2bf(s[mi][nj][j]);
        }

    // O += P @ V
    {
      char* Vb = (char*)&V_T[cb][0];
#pragma unroll
      for (int kk2 = 0; kk2 < 2; ++kk2) {
        bf16x8 pa0 = *(const bf16x8*)(Pb + w * 4096 + lr * 128 +
                                      ((kk2 * 64 + lg * 16) ^ ((lr & 7) << 4)));
        bf16x8 pa1 = *(const bf16x8*)(Pb + w * 4096 + (16 + lr) * 128 +
                                      ((kk2 * 64 + lg * 16) ^ ((lr & 7) << 4)));
#pragma unroll
        for (int nj = 0; nj < 8; ++nj) {
          bf16x8 vb = *(const bf16x8*)(Vb + (nj * 16 + lr) * 128 +
                                       ((kk2 * 64 + lg * 16) ^ ((lr & 7) << 4)));
          o[0][nj] = __builtin_amdgcn_mfma_f32_16x16x32_bf16(pa0, vb, o[0][nj], 0, 0, 0);
          o[1][nj] = __builtin_amdgcn_mfma_f32_16x16x32_bf16(pa1, vb, o[1][nj], 0, 0, 0);
        }
      }
    }

    if (more) WRITE_V(cb ^ 1);   // V regs -> LDS, after PV (latency hidden under compute)
    __syncthreads();
  }

  // normalize + store bf16 to aout[S, 2048]
#pragma unroll
  for (int mi = 0; mi < 2; ++mi)
#pragma unroll
    for (int j = 0; j < 4; ++j) {
      float inv = 1.0f / l_run[mi][j];
      int row = b * LSEQ + q0 + w * 32 + mi * 16 + lg * 4 + j;
#pragma unroll
      for (int nj = 0; nj < 8; ++nj)
        aout[(size_t)row * 2048 + h * 128 + nj * 16 + lr] = f2bf(o[mi][nj][j] * inv);
    }
}

extern "C" void kernel_launch(void* const* d_in, const int* in_sizes, int n_in,
                              void* d_out, int out_size, void* d_ws, size_t ws_size,
                              hipStream_t stream) {
  const float* x = (const float*)d_in[0];
  const float* wq = (const float*)d_in[1];
  const float* wk = (const float*)d_in[2];
  const float* wv = (const float*)d_in[3];
  const float* bq = (const float*)d_in[4];
  const float* bk = (const float*)d_in[5];
  const float* bv = (const float*)d_in[6];
  const float* wo = (const float*)d_in[7];
  const float* fc = (const float*)d_in[8];
  const int* pid = (const int*)d_in[9];

  char* ws = (char*)d_ws;
  unsigned short* xb = (unsigned short*)ws;                      // 8192*2048*2   = 33,554,432
  unsigned short* wqkvb = (unsigned short*)(ws + 33554432);      // 3072*2048*2   = 12,582,912
  unsigned short* wob = (unsigned short*)(ws + 46137344);        // 2048*2048*2   =  8,388,608
  float* bqkv = (float*)(ws + 54525952);                         // 3072*4        =     12,288
  unsigned short* qkv = (unsigned short*)(ws + 54538240);        // 8192*3072*2   = 50,331,648
  unsigned short* aout = xb;  // alias: xb fully consumed by QKV GEMM before attn writes

  hipMemcpyAsync(bqkv, bq, 2048 * 4, hipMemcpyDeviceToDevice, stream);
  hipMemcpyAsync(bqkv + 2048, bk, 512 * 4, hipMemcpyDeviceToDevice, stream);
  hipMemcpyAsync(bqkv + 2560, bv, 512 * 4, hipMemcpyDeviceToDevice, stream);

  conv_f2b<<<8192, 256, 0, stream>>>(x, xb, 2097152);
  conv_w3<<<3072, 256, 0, stream>>>(wq, wk, wv, wqkvb, 786432);
  conv_f2b<<<2048, 256, 0, stream>>>(wo, wob, 524288);

  gemm_bt<true, true><<<dim3(24, 64), 256, 0, stream>>>(xb, wqkvb, bqkv, qkv, 8192, 3072, 2048);
  rope_k<<<5120, 256, 0, stream>>>(qkv, fc, pid);
  attn_fwd<<<dim3(8, 16, 8), 256, 0, stream>>>(qkv, aout);
  gemm_bt<false, false><<<dim3(16, 64), 256, 0, stream>>>(aout, wob, nullptr, d_out, 8192, 2048, 2048);
}

// Round 6
// 622.302 us; speedup vs baseline: 1.1256x; 1.1256x over previous
//
#include <hip/hip_runtime.h>

#define S_TOK 8192
#define BATCH 8
#define LSEQ 1024
#define HID 2048
#define NH 16
#define NKV 4
#define DHEAD 128
#define QKV_W 3072
#define SCALE_F 0.08838834764831845f

typedef __attribute__((ext_vector_type(8))) unsigned short u16x8;
typedef __attribute__((ext_vector_type(8))) __bf16 bf16x8;
typedef __attribute__((ext_vector_type(4))) float f32x4;

__device__ __forceinline__ unsigned short f2bf(float f) {
  unsigned u = __builtin_bit_cast(unsigned, f);
  unsigned r = u + 0x7fffu + ((u >> 16) & 1u);
  return (unsigned short)(r >> 16);
}
__device__ __forceinline__ float bf2f(unsigned short h) {
  return __builtin_bit_cast(float, (unsigned)h << 16);
}

__device__ __forceinline__ void async16(const void* g, void* l) {
  __builtin_amdgcn_global_load_lds(
      (const __attribute__((address_space(1))) void*)g,
      (__attribute__((address_space(3))) void*)l, 16, 0, 0);
}

// ---------------- fp32 -> bf16 converters ----------------
__global__ __launch_bounds__(256) void conv_f2b(const float* __restrict__ src,
                                                unsigned short* __restrict__ dst,
                                                int n8) {
  int t = blockIdx.x * 256 + threadIdx.x;
  if (t >= n8) return;
  const f32x4* s4 = (const f32x4*)(src + (size_t)t * 8);
  f32x4 v0 = s4[0], v1 = s4[1];
  u16x8 o;
#pragma unroll
  for (int j = 0; j < 4; ++j) { o[j] = f2bf(v0[j]); o[4 + j] = f2bf(v1[j]); }
  *(u16x8*)(dst + (size_t)t * 8) = o;
}

// concat wq(2048,2048) wk(512,2048) wv(512,2048) -> bf16 (3072,2048)
__global__ __launch_bounds__(256) void conv_w3(const float* __restrict__ wq,
                                               const float* __restrict__ wk,
                                               const float* __restrict__ wv,
                                               unsigned short* __restrict__ dst,
                                               int n8) {
  int t = blockIdx.x * 256 + threadIdx.x;
  if (t >= n8) return;
  size_t idx = (size_t)t * 8;
  int row = (int)(idx >> 11);
  int col = (int)(idx & 2047);
  const float* src;
  if (row < 2048)      src = wq + ((size_t)row << 11) + col;
  else if (row < 2560) src = wk + ((size_t)(row - 2048) << 11) + col;
  else                 src = wv + ((size_t)(row - 2560) << 11) + col;
  const f32x4* s4 = (const f32x4*)src;
  f32x4 v0 = s4[0], v1 = s4[1];
  u16x8 o;
#pragma unroll
  for (int j = 0; j < 4; ++j) { o[j] = f2bf(v0[j]); o[4 + j] = f2bf(v1[j]); }
  *(u16x8*)(dst + idx) = o;
}

// ---------------- GEMM: C[M,N] = A[M,K] * B[N,K]^T (+bias) ----------------
// 128x128 tile, BK=32, 256 threads (4 waves, 2x2 of 64x64)
template <bool ADD_BIAS, bool OUT_BF16>
__global__ __launch_bounds__(256) void gemm_bt(const unsigned short* __restrict__ A,
                                               const unsigned short* __restrict__ Bw,
                                               const float* __restrict__ bias,
                                               void* __restrict__ Cout,
                                               int M, int N, int K) {
  __shared__ unsigned short A_lds[128 * 32];
  __shared__ unsigned short B_lds[128 * 32];
  const int tid = threadIdx.x;
  const int w = tid >> 6, lane = tid & 63;
  const int lr = lane & 15, lg = lane >> 4;
  const int wr = w >> 1, wc = w & 1;
  const int m0 = blockIdx.y * 128, n0 = blockIdx.x * 128;

  f32x4 acc[4][4];
#pragma unroll
  for (int mi = 0; mi < 4; ++mi)
#pragma unroll
    for (int nj = 0; nj < 4; ++nj) acc[mi][nj] = (f32x4){0.f, 0.f, 0.f, 0.f};

  const int nk = K >> 5;
  const int srow = (lane >> 2);       // 0..15 within chunk
  const int scol = (lane & 3) * 8;    // element col
  for (int kt = 0; kt < nk; ++kt) {
#pragma unroll
    for (int q = 0; q < 2; ++q) {
      int chunk = w * 2 + q;              // 0..7, 16 rows each
      int row = chunk * 16 + srow;
      async16(A + (size_t)(m0 + row) * K + kt * 32 + scol, &A_lds[chunk * 512]);
      async16(Bw + (size_t)(n0 + row) * K + kt * 32 + scol, &B_lds[chunk * 512]);
    }
    __syncthreads();
    bf16x8 a[4], bb[4];
#pragma unroll
    for (int mi = 0; mi < 4; ++mi)
      a[mi] = *(const bf16x8*)&A_lds[(wr * 64 + mi * 16 + lr) * 32 + lg * 8];
#pragma unroll
    for (int nj = 0; nj < 4; ++nj)
      bb[nj] = *(const bf16x8*)&B_lds[(wc * 64 + nj * 16 + lr) * 32 + lg * 8];
#pragma unroll
    for (int mi = 0; mi < 4; ++mi)
#pragma unroll
      for (int nj = 0; nj < 4; ++nj)
        acc[mi][nj] = __builtin_amdgcn_mfma_f32_16x16x32_bf16(a[mi], bb[nj], acc[mi][nj], 0, 0, 0);
    __syncthreads();
  }

#pragma unroll
  for (int mi = 0; mi < 4; ++mi)
#pragma unroll
    for (int nj = 0; nj < 4; ++nj)
#pragma unroll
      for (int j = 0; j < 4; ++j) {
        int row = m0 + wr * 64 + mi * 16 + lg * 4 + j;
        int col = n0 + wc * 64 + nj * 16 + lr;
        float v = acc[mi][nj][j];
        if (ADD_BIAS) v += bias[col];
        if (OUT_BF16)
          ((unsigned short*)Cout)[(size_t)row * N + col] = f2bf(v);
        else
          ((float*)Cout)[(size_t)row * N + col] = v;
      }
}

// ---------------- RoPE in-place on bf16 qkv (first 20 head-cols) ----------------
__global__ __launch_bounds__(256) void rope_k(unsigned short* __restrict__ qkv,
                                              const float* __restrict__ fc,
                                              const int* __restrict__ pid) {
  int t = blockIdx.x * 256 + threadIdx.x;  // 8192*20*8 threads
  int j0 = (t & 7) << 3;
  int hh = (t >> 3) % 20;
  int s = t / 160;
  if (s >= S_TOK) return;
  int sec = (j0 < 16) ? 0 : (j0 < 40 ? 1 : 2);
  int pos = pid[sec * S_TOK + s];
  const float* cs = fc + ((size_t)pos * 64 + j0) * 2;
  unsigned short* p = qkv + (size_t)s * QKV_W + hh * 128 + j0;
  u16x8 t1 = *(const u16x8*)p;
  u16x8 t2 = *(const u16x8*)(p + 64);
  u16x8 o1, o2;
#pragma unroll
  for (int j = 0; j < 8; ++j) {
    float c = cs[2 * j], sn = cs[2 * j + 1];
    float x1 = bf2f(t1[j]), x2 = bf2f(t2[j]);
    o1[j] = f2bf(x1 * c - x2 * sn);
    o2[j] = f2bf(x2 * c + x1 * sn);
  }
  *(u16x8*)p = o1;
  *(u16x8*)(p + 64) = o2;
}

// ---------------- causal GQA flash attention ----------------
// block: 256 thr (4 waves), QBLK=128 (32 rows/wave), KBLK=64
// Round-3 staging (single-buffer swizzled K via global_load_lds; reg-staged
// swizzled V^T; swizzled P). NEW: swapped QK^T (S^T = mfma(K,Q)) so the kv
// reduction is 15 in-reg ops + 2 shfl_xor instead of 8x(4 shfl) trees.
__global__ __launch_bounds__(256) void attn_fwd(const unsigned short* __restrict__ qkv,
                                                unsigned short* __restrict__ aout) {
  __shared__ unsigned short K_lds[64 * 128];   // [kv][d], swizzled
  __shared__ unsigned short V_T[128 * 64];     // [d][kv], swizzled
  __shared__ unsigned short P_lds[4 * 2048];   // per-wave [32 q][64 kv], swizzled
  char* Kb = (char*)K_lds;
  char* Vb = (char*)V_T;
  char* Pb = (char*)P_lds;
  const int tid = threadIdx.x, w = tid >> 6, lane = tid & 63;
  const int lr = lane & 15, lg = lane >> 4;
  const int q0 = (7 - (int)blockIdx.x) * 128;   // longest-first
  const int h = blockIdx.y, b = blockIdx.z, kvh = h >> 2;
  const size_t kvbase = (size_t)(b * LSEQ) * QKV_W;

  // Q fragments (B operand): rows w*32 + mi*16 + lr, d = kk*32 + lg*8
  bf16x8 qf[2][4];
#pragma unroll
  for (int mi = 0; mi < 2; ++mi)
#pragma unroll
    for (int kk = 0; kk < 4; ++kk)
      qf[mi][kk] = *(const bf16x8*)(qkv + kvbase + (size_t)(q0 + w * 32 + mi * 16 + lr) * QKV_W +
                                    h * 128 + kk * 32 + lg * 8);

  f32x4 o[2][8];
#pragma unroll
  for (int mi = 0; mi < 2; ++mi)
#pragma unroll
    for (int nj = 0; nj < 8; ++nj) o[mi][nj] = (f32x4){0.f, 0.f, 0.f, 0.f};
  // softmax state at q = q0 + w*32 + mi*16 + lr (lane-column layout)
  float m_run[2] = {-1e30f, -1e30f}, l_run[2] = {0.f, 0.f};

  const int ntiles = (q0 >> 6) + 2;
  for (int kt = 0; kt < ntiles; ++kt) {
    const int k0 = kt * 64;
    // stage K via global_load_lds, pre-swizzled global source
#pragma unroll
    for (int c4 = 0; c4 < 4; ++c4) {
      int chunk = w * 4 + c4;
      int row = chunk * 4 + lg;
      int colE = (lr * 8) ^ ((row & 7) * 8);
      async16(qkv + kvbase + (size_t)(k0 + row) * QKV_W + HID + kvh * 128 + colE,
              &K_lds[chunk * 512]);
    }
    // stage V transposed (reg->LDS, conflict-light swizzled writes)
#pragma unroll
    for (int r = 0; r < 4; ++r) {
      int d0 = (r * 4 + w) * 8;
      u16x8 vv = *(const u16x8*)(qkv + kvbase + (size_t)(k0 + lane) * QKV_W + HID + NKV * 128 +
                                 kvh * 128 + d0);
#pragma unroll
      for (int j = 0; j < 8; ++j)
        *(unsigned short*)(Vb + (d0 + j) * 128 + ((lane * 2) ^ (j << 4))) = vv[j];
    }
    __syncthreads();

    // S^T = K Q^T : D[kv = nj*16 + lg*4 + j][q = mi*16 + lr]
    f32x4 sT[4][2];
#pragma unroll
    for (int nj = 0; nj < 4; ++nj)
#pragma unroll
      for (int mi = 0; mi < 2; ++mi) sT[nj][mi] = (f32x4){0.f, 0.f, 0.f, 0.f};
    __builtin_amdgcn_s_setprio(1);
#pragma unroll
    for (int kk = 0; kk < 4; ++kk) {
#pragma unroll
      for (int nj = 0; nj < 4; ++nj) {
        bf16x8 kb = *(const bf16x8*)(Kb + (nj * 16 + lr) * 256 +
                                     ((kk * 64 + lg * 16) ^ ((lr & 7) << 4)));
        sT[nj][0] = __builtin_amdgcn_mfma_f32_16x16x32_bf16(kb, qf[0][kk], sT[nj][0], 0, 0, 0);
        sT[nj][1] = __builtin_amdgcn_mfma_f32_16x16x32_bf16(kb, qf[1][kk], sT[nj][1], 0, 0, 0);
      }
    }
    __builtin_amdgcn_s_setprio(0);

    // online softmax over kv (in-register per q-column, 2 shfls per mi)
    float sc[2];
#pragma unroll
    for (int mi = 0; mi < 2; ++mi) {
      int qg = q0 + w * 32 + mi * 16 + lr;
      float vmax = -1e30f;
#pragma unroll
      for (int nj = 0; nj < 4; ++nj)
#pragma unroll
        for (int j = 0; j < 4; ++j) {
          int kvg = k0 + nj * 16 + lg * 4 + j;
          float v = sT[nj][mi][j] * SCALE_F;
          v = (kvg > qg) ? -1e30f : v;
          sT[nj][mi][j] = v;
          vmax = fmaxf(vmax, v);
        }
      vmax = fmaxf(vmax, __shfl_xor(vmax, 16, 64));
      vmax = fmaxf(vmax, __shfl_xor(vmax, 32, 64));
      float mn = fmaxf(m_run[mi], vmax);
      sc[mi] = __expf(m_run[mi] - mn);
      m_run[mi] = mn;
      float rs = 0.f;
#pragma unroll
      for (int nj = 0; nj < 4; ++nj)
#pragma unroll
        for (int j = 0; j < 4; ++j) {
          float p = __expf(sT[nj][mi][j] - mn);
          sT[nj][mi][j] = p;
          rs += p;
        }
      rs += __shfl_xor(rs, 16, 64);
      rs += __shfl_xor(rs, 32, 64);
      l_run[mi] = l_run[mi] * sc[mi] + rs;
    }

    // write P to per-wave LDS: [q = mi*16+lr][kv = nj*16+lg*4+j], swizzled
#pragma unroll
    for (int mi = 0; mi < 2; ++mi) {
      int prow = mi * 16 + lr;
#pragma unroll
      for (int nj = 0; nj < 4; ++nj)
#pragma unroll
        for (int j = 0; j < 4; ++j) {
          int pcol = nj * 16 + lg * 4 + j;
          *(unsigned short*)(Pb + w * 4096 + prow * 128 + ((pcol * 2) ^ ((prow & 7) << 4))) =
              f2bf(sT[nj][mi][j]);
        }
    }

    // broadcast rescale factor to o-row layout (row q = mi*16 + lg*4 + j)
    float sfb[2][4];
#pragma unroll
    for (int mi = 0; mi < 2; ++mi)
#pragma unroll
      for (int j = 0; j < 4; ++j) sfb[mi][j] = __shfl(sc[mi], lg * 4 + j, 64);
#pragma unroll
    for (int mi = 0; mi < 2; ++mi)
#pragma unroll
      for (int nj = 0; nj < 8; ++nj)
#pragma unroll
        for (int j = 0; j < 4; ++j) o[mi][nj][j] *= sfb[mi][j];

    // O += P @ V
    __builtin_amdgcn_s_setprio(1);
#pragma unroll
    for (int kk2 = 0; kk2 < 2; ++kk2) {
      bf16x8 pa0 = *(const bf16x8*)(Pb + w * 4096 + lr * 128 +
                                    ((kk2 * 64 + lg * 16) ^ ((lr & 7) << 4)));
      bf16x8 pa1 = *(const bf16x8*)(Pb + w * 4096 + (16 + lr) * 128 +
                                    ((kk2 * 64 + lg * 16) ^ ((lr & 7) << 4)));
#pragma unroll
      for (int nj = 0; nj < 8; ++nj) {
        bf16x8 vb = *(const bf16x8*)(Vb + (nj * 16 + lr) * 128 +
                                     ((kk2 * 64 + lg * 16) ^ ((lr & 7) << 4)));
        o[0][nj] = __builtin_amdgcn_mfma_f32_16x16x32_bf16(pa0, vb, o[0][nj], 0, 0, 0);
        o[1][nj] = __builtin_amdgcn_mfma_f32_16x16x32_bf16(pa1, vb, o[1][nj], 0, 0, 0);
      }
    }
    __builtin_amdgcn_s_setprio(0);
    __syncthreads();
  }

  // normalize + store bf16 to aout[S, 2048]
  float lb[2][4];
#pragma unroll
  for (int mi = 0; mi < 2; ++mi)
#pragma unroll
    for (int j = 0; j < 4; ++j) lb[mi][j] = __shfl(l_run[mi], lg * 4 + j, 64);
#pragma unroll
  for (int mi = 0; mi < 2; ++mi)
#pragma unroll
    for (int j = 0; j < 4; ++j) {
      float inv = 1.0f / lb[mi][j];
      int row = b * LSEQ + q0 + w * 32 + mi * 16 + lg * 4 + j;
#pragma unroll
      for (int nj = 0; nj < 8; ++nj)
        aout[(size_t)row * 2048 + h * 128 + nj * 16 + lr] = f2bf(o[mi][nj][j] * inv);
    }
}

extern "C" void kernel_launch(void* const* d_in, const int* in_sizes, int n_in,
                              void* d_out, int out_size, void* d_ws, size_t ws_size,
                              hipStream_t stream) {
  const float* x = (const float*)d_in[0];
  const float* wq = (const float*)d_in[1];
  const float* wk = (const float*)d_in[2];
  const float* wv = (const float*)d_in[3];
  const float* bq = (const float*)d_in[4];
  const float* bk = (const float*)d_in[5];
  const float* bv = (const float*)d_in[6];
  const float* wo = (const float*)d_in[7];
  const float* fc = (const float*)d_in[8];
  const int* pid = (const int*)d_in[9];

  char* ws = (char*)d_ws;
  unsigned short* xb = (unsigned short*)ws;                      // 8192*2048*2   = 33,554,432
  unsigned short* wqkvb = (unsigned short*)(ws + 33554432);      // 3072*2048*2   = 12,582,912
  unsigned short* wob = (unsigned short*)(ws + 46137344);        // 2048*2048*2   =  8,388,608
  float* bqkv = (float*)(ws + 54525952);                         // 3072*4        =     12,288
  unsigned short* qkv = (unsigned short*)(ws + 54538240);        // 8192*3072*2   = 50,331,648
  unsigned short* aout = xb;  // alias: xb fully consumed by QKV GEMM before attn writes

  hipMemcpyAsync(bqkv, bq, 2048 * 4, hipMemcpyDeviceToDevice, stream);
  hipMemcpyAsync(bqkv + 2048, bk, 512 * 4, hipMemcpyDeviceToDevice, stream);
  hipMemcpyAsync(bqkv + 2560, bv, 512 * 4, hipMemcpyDeviceToDevice, stream);

  conv_f2b<<<8192, 256, 0, stream>>>(x, xb, 2097152);
  conv_w3<<<3072, 256, 0, stream>>>(wq, wk, wv, wqkvb, 786432);
  conv_f2b<<<2048, 256, 0, stream>>>(wo, wob, 524288);

  gemm_bt<true, true><<<dim3(24, 64), 256, 0, stream>>>(xb, wqkvb, bqkv, qkv, 8192, 3072, 2048);
  rope_k<<<5120, 256, 0, stream>>>(qkv, fc, pid);
  attn_fwd<<<dim3(8, 16, 8), 256, 0, stream>>>(qkv, aout);
  gemm_bt<false, false><<<dim3(16, 64), 256, 0, stream>>>(aout, wob, nullptr, d_out, 8192, 2048, 2048);
}